// Round 1
// baseline (114.738 us; speedup 1.0000x reference)
//
#include <hip/hip_runtime.h>

#define N 1024
#define E 256
#define H 128

// context = relu(x @ Wc + bc)   [H]
__global__ void ctx_kernel(const float* __restrict__ x, const float* __restrict__ Wc,
                           const float* __restrict__ bc, float* __restrict__ ctx) {
    int h = threadIdx.x;  // 128 threads
    float acc = bc[h];
    for (int e = 0; e < E; ++e) acc += x[e] * Wc[e * H + h];
    ctx[h] = fmaxf(acc, 0.f);
}

// Per row i:
//   queries = P[i] @ Wq + bq + ctx ; keys = P[i] @ Wk + bk + ctx
//   qp[i] = queries @ W1[:H] + b1  ; kp[i] = keys @ W1[H:]
__global__ void proj_kernel(const float* __restrict__ P,
                            const float* __restrict__ Wq, const float* __restrict__ bq,
                            const float* __restrict__ Wk, const float* __restrict__ bk,
                            const float* __restrict__ W1, const float* __restrict__ b1,
                            const float* __restrict__ ctx,
                            float* __restrict__ qp, float* __restrict__ kp) {
    __shared__ float prow[E];
    __shared__ float qrow[H];
    __shared__ float krow[H];
    int i = blockIdx.x;
    int h = threadIdx.x;  // 128 threads
    prow[h]     = P[i * E + h];
    prow[h + H] = P[i * E + h + H];
    __syncthreads();
    float c = ctx[h];
    float sq = bq[h] + c;
    float sk = bk[h] + c;
    for (int e = 0; e < E; ++e) {
        float p = prow[e];
        sq += p * Wq[e * H + h];   // coalesced across h
        sk += p * Wk[e * H + h];
    }
    qrow[h] = sq;
    krow[h] = sk;
    __syncthreads();
    float aq = b1[h];
    float ak = 0.f;
    for (int r = 0; r < H; ++r) {
        aq += qrow[r] * W1[r * H + h];
        ak += krow[r] * W1[(H + r) * H + h];
    }
    qp[i * H + h] = aq;
    kp[i * H + h] = ak;
}

// scores[i,j] = sum_h relu(qp[i][h] + kp[j][h]) * W2[h] + b2, packed triu (i<j)
__global__ __launch_bounds__(256) void pair_kernel(
    const float* __restrict__ qp, const float* __restrict__ kp,
    const float* __restrict__ W2, const float* __restrict__ b2,
    float* __restrict__ out) {
    int bi = blockIdx.y, bj = blockIdx.x;
    if (bj < bi) return;  // strictly-below-diagonal tile: nothing to do

    // stride 132 floats = 528 B: 16B-aligned rows, conflict-free b128 pattern
    __shared__ __align__(16) float qs[32][132];
    __shared__ __align__(16) float ks[32][132];
    __shared__ __align__(16) float w2s[H];

    int t = threadIdx.x;  // 256 threads
    if (t < H) w2s[t] = W2[t];

    const float4* qp4 = (const float4*)(qp + bi * 32 * H);
    const float4* kp4 = (const float4*)(kp + bj * 32 * H);
#pragma unroll
    for (int v = 0; v < 4; ++v) {
        int idx = v * 256 + t;        // 0..1023 float4s
        int r = idx >> 5, c = idx & 31;
        float4 q = qp4[r * 32 + c];
        float4 k = kp4[r * 32 + c];
        *((float4*)&qs[r][c * 4]) = q;
        *((float4*)&ks[r][c * 4]) = k;
    }
    __syncthreads();

    int tj  = t & 31;       // kp row within tile (fixed per thread)
    int ti0 = t >> 5;       // qp rows ti0, ti0+8, ti0+16, ti0+24
    float b2v = b2[0];
    float acc[4];
#pragma unroll
    for (int u = 0; u < 4; ++u) acc[u] = b2v;

    const float4* ksr = (const float4*)&ks[tj][0];
    const float4* w24 = (const float4*)&w2s[0];
    for (int h4 = 0; h4 < 32; ++h4) {
        float4 k4 = ksr[h4];
        float4 w4 = w24[h4];
#pragma unroll
        for (int u = 0; u < 4; ++u) {
            const float4 q4 = *((const float4*)&qs[ti0 + u * 8][h4 * 4]);
            acc[u] += fmaxf(q4.x + k4.x, 0.f) * w4.x;
            acc[u] += fmaxf(q4.y + k4.y, 0.f) * w4.y;
            acc[u] += fmaxf(q4.z + k4.z, 0.f) * w4.z;
            acc[u] += fmaxf(q4.w + k4.w, 0.f) * w4.w;
        }
    }

#pragma unroll
    for (int u = 0; u < 4; ++u) {
        int i = bi * 32 + ti0 + u * 8;
        int j = bj * 32 + tj;
        if (j > i) {
            int base = i * (2 * N - i - 1) / 2;  // pairs before row i
            out[base + (j - i - 1)] = acc[u];    // coalesced within a wave
        }
    }
}

extern "C" void kernel_launch(void* const* d_in, const int* in_sizes, int n_in,
                              void* d_out, int out_size, void* d_ws, size_t ws_size,
                              hipStream_t stream) {
    const float* x  = (const float*)d_in[0];   // next_state_embedding [256]
    const float* P  = (const float*)d_in[1];   // prev_variable_embeddings [1024,256]
    const float* Wq = (const float*)d_in[2];
    const float* bq = (const float*)d_in[3];
    const float* Wk = (const float*)d_in[4];
    const float* bk = (const float*)d_in[5];
    const float* Wc = (const float*)d_in[6];
    const float* bc = (const float*)d_in[7];
    const float* W1 = (const float*)d_in[8];   // [256,128]
    const float* b1 = (const float*)d_in[9];
    const float* W2 = (const float*)d_in[10];  // [128,1]
    const float* b2 = (const float*)d_in[11];  // [1]
    float* out = (float*)d_out;

    float* ws  = (float*)d_ws;
    float* ctx = ws;                 // 128
    float* qp  = ws + 128;           // 1024*128
    float* kp  = qp + N * H;         // 1024*128

    ctx_kernel<<<1, 128, 0, stream>>>(x, Wc, bc, ctx);
    proj_kernel<<<N, 128, 0, stream>>>(P, Wq, bq, Wk, bk, W1, b1, ctx, qp, kp);
    dim3 grid(32, 32);
    pair_kernel<<<grid, 256, 0, stream>>>(qp, kp, W2, b2, out);
}

// Round 3
// 103.755 us; speedup vs baseline: 1.1059x; 1.1059x over previous
//
#include <hip/hip_runtime.h>

#define N 1024
#define E 256
#define H 128

typedef _Float16 hv2 __attribute__((ext_vector_type(2)));
typedef _Float16 half_t;

__device__ __forceinline__ float dot2_acc(hv2 a, hv2 b, float c) {
#if __has_builtin(__builtin_amdgcn_fdot2)
    return __builtin_amdgcn_fdot2(a, b, c, false);
#else
    return c + (float)a.x * (float)b.x + (float)a.y * (float)b.y;
#endif
}

__device__ __forceinline__ hv2 relu_add2(hv2 a, hv2 b) {
    hv2 s = a + b;
    hv2 z = (hv2)(_Float16)0.f;
    return __builtin_elementwise_max(s, z);
}

// Setup: blocks 0..255 compute Wq' = Wq@W1a, Wk' = Wk@W1b (one row each).
// Block 256 computes ctx = relu(x@Wc+bc), then constq=(bq+ctx)@W1a+b1,
// constk=(bk+ctx)@W1b.
__global__ __launch_bounds__(256) void setup_kernel(
    const float* __restrict__ x, const float* __restrict__ Wc, const float* __restrict__ bc,
    const float* __restrict__ Wq, const float* __restrict__ bq,
    const float* __restrict__ Wk, const float* __restrict__ bk,
    const float* __restrict__ W1, const float* __restrict__ b1,
    float* __restrict__ Wqp, float* __restrict__ Wkp,
    float* __restrict__ constq, float* __restrict__ constk) {
    int b = blockIdx.x;
    int t = threadIdx.x;
    if (b < E) {
        __shared__ float wq_s[H], wk_s[H];
        if (t < H) wq_s[t] = Wq[b * H + t];
        else       wk_s[t - H] = Wk[b * H + (t - H)];
        __syncthreads();
        int h = t & (H - 1);
        float acc = 0.f;
        if (t < H) {
#pragma unroll 8
            for (int r = 0; r < H; ++r) acc += wq_s[r] * W1[r * H + h];
            Wqp[b * H + h] = acc;
        } else {
#pragma unroll 8
            for (int r = 0; r < H; ++r) acc += wk_s[r] * W1[(H + r) * H + h];
            Wkp[b * H + h] = acc;
        }
    } else {
        __shared__ float xs[E];
        __shared__ float pc[2][H];
        __shared__ float aq_s[H], ak_s[H];
        xs[t] = x[t];
        __syncthreads();
        int h = t & (H - 1);
        int c = t >> 7;  // 0 or 1
        float p = 0.f;
#pragma unroll 8
        for (int e = c * H; e < c * H + H; ++e) p += xs[e] * Wc[e * H + h];
        pc[c][h] = p;
        __syncthreads();
        if (t < H) {
            float ctxv = fmaxf(pc[0][t] + pc[1][t] + bc[t], 0.f);
            aq_s[t] = bq[t] + ctxv;
            ak_s[t] = bk[t] + ctxv;
        }
        __syncthreads();
        float acc;
        if (t < H) {
            acc = b1[h];
#pragma unroll 8
            for (int r = 0; r < H; ++r) acc += aq_s[r] * W1[r * H + h];
            constq[h] = acc;
        } else {
            acc = 0.f;
#pragma unroll 8
            for (int r = 0; r < H; ++r) acc += ak_s[r] * W1[(H + r) * H + h];
            constk[h] = acc;
        }
    }
}

// proj: 4 rows per block. qp[i] = P[i]@Wq' + constq (f16 out); kp likewise.
__global__ __launch_bounds__(256) void proj_kernel(
    const float* __restrict__ P,
    const float* __restrict__ Wqp, const float* __restrict__ Wkp,
    const float* __restrict__ constq, const float* __restrict__ constk,
    half_t* __restrict__ qh, half_t* __restrict__ kh) {
    __shared__ __align__(16) float p_s[4 * E];
    int b = blockIdx.x;
    int i0 = b * 4;
    int t = threadIdx.x;
    ((float4*)p_s)[t] = ((const float4*)(P + i0 * E))[t];
    __syncthreads();
    bool isq = t < H;
    int h = t & (H - 1);
    const float* M = isq ? Wqp : Wkp;
    float cv = isq ? constq[h] : constk[h];
    float a0 = cv, a1 = cv, a2 = cv, a3 = cv;
    for (int e = 0; e < E; e += 4) {
        float4 p0 = *(const float4*)&p_s[0 * E + e];
        float4 p1 = *(const float4*)&p_s[1 * E + e];
        float4 p2 = *(const float4*)&p_s[2 * E + e];
        float4 p3 = *(const float4*)&p_s[3 * E + e];
        float m0 = M[(e + 0) * H + h];
        float m1 = M[(e + 1) * H + h];
        float m2 = M[(e + 2) * H + h];
        float m3 = M[(e + 3) * H + h];
        a0 += p0.x * m0 + p0.y * m1 + p0.z * m2 + p0.w * m3;
        a1 += p1.x * m0 + p1.y * m1 + p1.z * m2 + p1.w * m3;
        a2 += p2.x * m0 + p2.y * m1 + p2.z * m2 + p2.w * m3;
        a3 += p3.x * m0 + p3.y * m1 + p3.z * m2 + p3.w * m3;
    }
    half_t* O = isq ? qh : kh;
    O[(i0 + 0) * H + h] = (half_t)a0;
    O[(i0 + 1) * H + h] = (half_t)a1;
    O[(i0 + 2) * H + h] = (half_t)a2;
    O[(i0 + 3) * H + h] = (half_t)a3;
}

// pair: tiles of 32 i-rows x 64 j-rows; 8 pairs/thread; f16 LDS + fdot2.
#define QSTR 136  // halves; 272 B row stride -> odd count of 16B superbanks -> conflict-free b128
__global__ __launch_bounds__(256) void pair_kernel(
    const half_t* __restrict__ qh, const half_t* __restrict__ kh,
    const float* __restrict__ W2, const float* __restrict__ b2,
    float* __restrict__ out) {
    int bj = blockIdx.x;  // 0..15, j in [bj*64, bj*64+64)
    int bi = blockIdx.y;  // 0..31, i in [bi*32, bi*32+32)
    if (bj * 64 + 63 <= bi * 32) return;  // no j > i in this tile

    __shared__ __align__(16) half_t qs[32][QSTR];
    __shared__ __align__(16) half_t ks[64][QSTR];
    __shared__ __align__(16) half_t w2s[H];

    int t = threadIdx.x;
    if (t < H) w2s[t] = (half_t)W2[t];

    const float4* qh4 = (const float4*)(qh + bi * 32 * H);
    const float4* kh4 = (const float4*)(kh + bj * 64 * H);
#pragma unroll
    for (int v = 0; v < 2; ++v) {
        int idx = v * 256 + t;           // 0..511 : 32 rows x 16 float4
        int r = idx >> 4, c = idx & 15;
        float4 q = qh4[idx];
        *(float4*)&qs[r][c * 8] = q;
    }
#pragma unroll
    for (int v = 0; v < 4; ++v) {
        int idx = v * 256 + t;           // 0..1023 : 64 rows x 16 float4
        int r = idx >> 4, c = idx & 15;
        float4 k = kh4[idx];
        *(float4*)&ks[r][c * 8] = k;
    }
    __syncthreads();

    int jj  = t & 31;    // k rows jj, jj+32
    int ti0 = t >> 5;    // q rows ti0, ti0+8, ti0+16, ti0+24
    float b2v = b2[0];
    float acc[4][2];
#pragma unroll
    for (int u = 0; u < 4; ++u) { acc[u][0] = b2v; acc[u][1] = b2v; }

    for (int h8 = 0; h8 < 16; ++h8) {
        float4 wf = *(const float4*)&w2s[h8 * 8];
        float4 ka = *(const float4*)&ks[jj][h8 * 8];
        float4 kb = *(const float4*)&ks[jj + 32][h8 * 8];
        const hv2* wp  = (const hv2*)&wf;
        const hv2* kap = (const hv2*)&ka;
        const hv2* kbp = (const hv2*)&kb;
#pragma unroll
        for (int u = 0; u < 4; ++u) {
            float4 qf = *(const float4*)&qs[ti0 + u * 8][h8 * 8];
            const hv2* qp2 = (const hv2*)&qf;
#pragma unroll
            for (int s = 0; s < 4; ++s) {
                hv2 sa = relu_add2(qp2[s], kap[s]);
                hv2 sb = relu_add2(qp2[s], kbp[s]);
                acc[u][0] = dot2_acc(sa, wp[s], acc[u][0]);
                acc[u][1] = dot2_acc(sb, wp[s], acc[u][1]);
            }
        }
    }

#pragma unroll
    for (int u = 0; u < 4; ++u) {
        int i = bi * 32 + ti0 + u * 8;
#pragma unroll
        for (int jv = 0; jv < 2; ++jv) {
            int j = bj * 64 + jj + jv * 32;
            if (j > i) {
                int base = i * (2 * N - i - 1) / 2;
                out[base + (j - i - 1)] = acc[u][jv];
            }
        }
    }
}

extern "C" void kernel_launch(void* const* d_in, const int* in_sizes, int n_in,
                              void* d_out, int out_size, void* d_ws, size_t ws_size,
                              hipStream_t stream) {
    const float* x  = (const float*)d_in[0];
    const float* P  = (const float*)d_in[1];
    const float* Wq = (const float*)d_in[2];
    const float* bq = (const float*)d_in[3];
    const float* Wk = (const float*)d_in[4];
    const float* bk = (const float*)d_in[5];
    const float* Wc = (const float*)d_in[6];
    const float* bc = (const float*)d_in[7];
    const float* W1 = (const float*)d_in[8];
    const float* b1 = (const float*)d_in[9];
    const float* W2 = (const float*)d_in[10];
    const float* b2 = (const float*)d_in[11];
    float* out = (float*)d_out;

    float* ws     = (float*)d_ws;
    float* constq = ws;                      // 128
    float* constk = ws + H;                  // 128
    float* Wqp    = ws + 2 * H;              // 256*128
    float* Wkp    = Wqp + E * H;             // 256*128
    half_t* qh    = (half_t*)(Wkp + E * H);  // 1024*128 halves
    half_t* kh    = qh + N * H;              // 1024*128 halves

    setup_kernel<<<E + 1, 256, 0, stream>>>(x, Wc, bc, Wq, bq, Wk, bk, W1, b1,
                                            Wqp, Wkp, constq, constk);
    proj_kernel<<<N / 4, 256, 0, stream>>>(P, Wqp, Wkp, constq, constk, qh, kh);
    dim3 grid(16, 32);
    pair_kernel<<<grid, 256, 0, stream>>>(qh, kh, W2, b2, out);
}

// Round 4
// 102.119 us; speedup vs baseline: 1.1236x; 1.0160x over previous
//
#include <hip/hip_runtime.h>

#define N 1024
#define E 256
#define H 128

typedef _Float16 hv2 __attribute__((ext_vector_type(2)));
typedef _Float16 half_t;

__device__ __forceinline__ float dot2_acc(hv2 a, hv2 b, float c) {
#if __has_builtin(__builtin_amdgcn_fdot2)
    return __builtin_amdgcn_fdot2(a, b, c, false);
#else
    return c + (float)a.x * (float)b.x + (float)a.y * (float)b.y;
#endif
}

__device__ __forceinline__ hv2 relu_add2(hv2 a, hv2 b) {
    hv2 s = a + b;
    hv2 z = (hv2)(_Float16)0.f;
    return __builtin_elementwise_max(s, z);
}

// Setup: blocks 0..255 compute Wq' = Wq@W1a, Wk' = Wk@W1b (one row each).
// Block 256 computes ctx = relu(x@Wc+bc), then constq=(bq+ctx)@W1a+b1,
// constk=(bk+ctx)@W1b.
__global__ __launch_bounds__(256) void setup_kernel(
    const float* __restrict__ x, const float* __restrict__ Wc, const float* __restrict__ bc,
    const float* __restrict__ Wq, const float* __restrict__ bq,
    const float* __restrict__ Wk, const float* __restrict__ bk,
    const float* __restrict__ W1, const float* __restrict__ b1,
    float* __restrict__ Wqp, float* __restrict__ Wkp,
    float* __restrict__ constq, float* __restrict__ constk) {
    int b = blockIdx.x;
    int t = threadIdx.x;
    if (b < E) {
        __shared__ float wq_s[H], wk_s[H];
        if (t < H) wq_s[t] = Wq[b * H + t];
        else       wk_s[t - H] = Wk[b * H + (t - H)];
        __syncthreads();
        int h = t & (H - 1);
        float acc = 0.f;
        if (t < H) {
#pragma unroll 8
            for (int r = 0; r < H; ++r) acc += wq_s[r] * W1[r * H + h];
            Wqp[b * H + h] = acc;
        } else {
#pragma unroll 8
            for (int r = 0; r < H; ++r) acc += wk_s[r] * W1[(H + r) * H + h];
            Wkp[b * H + h] = acc;
        }
    } else {
        __shared__ float xs[E];
        __shared__ float pc[2][H];
        __shared__ float aq_s[H], ak_s[H];
        xs[t] = x[t];
        __syncthreads();
        int h = t & (H - 1);
        int c = t >> 7;  // 0 or 1
        float p = 0.f;
#pragma unroll 8
        for (int e = c * H; e < c * H + H; ++e) p += xs[e] * Wc[e * H + h];
        pc[c][h] = p;
        __syncthreads();
        if (t < H) {
            float ctxv = fmaxf(pc[0][t] + pc[1][t] + bc[t], 0.f);
            aq_s[t] = bq[t] + ctxv;
            ak_s[t] = bk[t] + ctxv;
        }
        __syncthreads();
        float acc;
        if (t < H) {
            acc = b1[h];
#pragma unroll 8
            for (int r = 0; r < H; ++r) acc += aq_s[r] * W1[r * H + h];
            constq[h] = acc;
        } else {
            acc = 0.f;
#pragma unroll 8
            for (int r = 0; r < H; ++r) acc += ak_s[r] * W1[(H + r) * H + h];
            constk[h] = acc;
        }
    }
}

// proj: 4 rows per block. qp[i] = P[i]@Wq' + constq (f16 out); kp likewise.
__global__ __launch_bounds__(256) void proj_kernel(
    const float* __restrict__ P,
    const float* __restrict__ Wqp, const float* __restrict__ Wkp,
    const float* __restrict__ constq, const float* __restrict__ constk,
    half_t* __restrict__ qh, half_t* __restrict__ kh) {
    __shared__ __align__(16) float p_s[4 * E];
    int b = blockIdx.x;
    int i0 = b * 4;
    int t = threadIdx.x;
    ((float4*)p_s)[t] = ((const float4*)(P + i0 * E))[t];
    __syncthreads();
    bool isq = t < H;
    int h = t & (H - 1);
    const float* M = isq ? Wqp : Wkp;
    float cv = isq ? constq[h] : constk[h];
    float a0 = cv, a1 = cv, a2 = cv, a3 = cv;
    for (int e = 0; e < E; e += 4) {
        float4 p0 = *(const float4*)&p_s[0 * E + e];
        float4 p1 = *(const float4*)&p_s[1 * E + e];
        float4 p2 = *(const float4*)&p_s[2 * E + e];
        float4 p3 = *(const float4*)&p_s[3 * E + e];
        float m0 = M[(e + 0) * H + h];
        float m1 = M[(e + 1) * H + h];
        float m2 = M[(e + 2) * H + h];
        float m3 = M[(e + 3) * H + h];
        a0 += p0.x * m0 + p0.y * m1 + p0.z * m2 + p0.w * m3;
        a1 += p1.x * m0 + p1.y * m1 + p1.z * m2 + p1.w * m3;
        a2 += p2.x * m0 + p2.y * m1 + p2.z * m2 + p2.w * m3;
        a3 += p3.x * m0 + p3.y * m1 + p3.z * m2 + p3.w * m3;
    }
    half_t* O = isq ? qh : kh;
    O[(i0 + 0) * H + h] = (half_t)a0;
    O[(i0 + 1) * H + h] = (half_t)a1;
    O[(i0 + 2) * H + h] = (half_t)a2;
    O[(i0 + 3) * H + h] = (half_t)a3;
}

// pair: exact triangular tiling. 528 blocks, one 32x32 (bi<=bj) tile each.
// Per thread: 4 (i,j) pairs; f16 LDS + fdot2.
#define QSTR 136  // halves; 272 B row stride -> odd count of 16B superbanks -> conflict-free b128
#define NTILE 32  // 32 row-tiles of 32
__global__ __launch_bounds__(256) void pair_kernel(
    const half_t* __restrict__ qh, const half_t* __restrict__ kh,
    const float* __restrict__ W2, const float* __restrict__ b2,
    float* __restrict__ out) {
    // map linear tile id -> (bi, bj), bi <= bj, row-major upper-tri incl diag
    int tid = blockIdx.x;
    int bi = (int)((65.0f - sqrtf(4225.0f - 8.0f * (float)tid)) * 0.5f);
    // fixup against fp error: base(bi) = 32*bi - bi*(bi-1)/2
    while (bi > 0 && tid < 32 * bi - bi * (bi - 1) / 2) --bi;
    while (tid >= 32 * (bi + 1) - (bi + 1) * bi / 2) ++bi;
    int bj = bi + (tid - (32 * bi - bi * (bi - 1) / 2));

    __shared__ __align__(16) half_t qs[32][QSTR];
    __shared__ __align__(16) half_t ks[32][QSTR];
    __shared__ __align__(16) half_t w2s[H];

    int t = threadIdx.x;
    if (t < H) w2s[t] = (half_t)W2[t];

    const float4* qh4 = (const float4*)(qh + bi * 32 * H);
    const float4* kh4 = (const float4*)(kh + bj * 32 * H);
#pragma unroll
    for (int v = 0; v < 2; ++v) {
        int idx = v * 256 + t;           // 0..511 : 32 rows x 16 float4
        int r = idx >> 4, c = idx & 15;
        float4 q = qh4[idx];
        float4 k = kh4[idx];
        *(float4*)&qs[r][c * 8] = q;
        *(float4*)&ks[r][c * 8] = k;
    }
    __syncthreads();

    int jj  = t & 31;    // k row within tile
    int ti0 = t >> 5;    // q rows ti0, ti0+8, ti0+16, ti0+24
    float b2v = b2[0];
    float acc[4];
#pragma unroll
    for (int u = 0; u < 4; ++u) acc[u] = b2v;

    for (int h8 = 0; h8 < 16; ++h8) {
        float4 wf = *(const float4*)&w2s[h8 * 8];
        float4 kv = *(const float4*)&ks[jj][h8 * 8];
        const hv2* wp = (const hv2*)&wf;
        const hv2* kp2 = (const hv2*)&kv;
#pragma unroll
        for (int u = 0; u < 4; ++u) {
            float4 qf = *(const float4*)&qs[ti0 + u * 8][h8 * 8];
            const hv2* qp2 = (const hv2*)&qf;
#pragma unroll
            for (int s = 0; s < 4; ++s) {
                hv2 sa = relu_add2(qp2[s], kp2[s]);
                acc[u] = dot2_acc(sa, wp[s], acc[u]);
            }
        }
    }

#pragma unroll
    for (int u = 0; u < 4; ++u) {
        int i = bi * 32 + ti0 + u * 8;
        int j = bj * 32 + jj;
        if (j > i) {
            int base = i * (2 * N - i - 1) / 2;
            out[base + (j - i - 1)] = acc[u];
        }
    }
}

extern "C" void kernel_launch(void* const* d_in, const int* in_sizes, int n_in,
                              void* d_out, int out_size, void* d_ws, size_t ws_size,
                              hipStream_t stream) {
    const float* x  = (const float*)d_in[0];
    const float* P  = (const float*)d_in[1];
    const float* Wq = (const float*)d_in[2];
    const float* bq = (const float*)d_in[3];
    const float* Wk = (const float*)d_in[4];
    const float* bk = (const float*)d_in[5];
    const float* Wc = (const float*)d_in[6];
    const float* bc = (const float*)d_in[7];
    const float* W1 = (const float*)d_in[8];
    const float* b1 = (const float*)d_in[9];
    const float* W2 = (const float*)d_in[10];
    const float* b2 = (const float*)d_in[11];
    float* out = (float*)d_out;

    float* ws     = (float*)d_ws;
    float* constq = ws;                      // 128
    float* constk = ws + H;                  // 128
    float* Wqp    = ws + 2 * H;              // 256*128
    float* Wkp    = Wqp + E * H;             // 256*128
    half_t* qh    = (half_t*)(Wkp + E * H);  // 1024*128 halves
    half_t* kh    = qh + N * H;              // 1024*128 halves

    setup_kernel<<<E + 1, 256, 0, stream>>>(x, Wc, bc, Wq, bq, Wk, bk, W1, b1,
                                            Wqp, Wkp, constq, constk);
    proj_kernel<<<N / 4, 256, 0, stream>>>(P, Wqp, Wkp, constq, constk, qh, kh);
    pair_kernel<<<528, 256, 0, stream>>>(qh, kh, W2, b2, out);
}